// Round 7
// baseline (177.792 us; speedup 1.0000x reference)
//
#include <hip/hip_runtime.h>
#include <hip/hip_bf16.h>
#include <cstdint>

// Problem constants
#define NB   2
#define NC   256
#define NN   4096   // H*W = 64*64
#define NH   8      // heads
#define HSZ  32     // head size
#define NF   256    // FEAT
#define N3F  768

typedef __bf16 bf16x8 __attribute__((ext_vector_type(8)));
typedef __bf16 bf16x4 __attribute__((ext_vector_type(4)));
typedef short  s16x4  __attribute__((ext_vector_type(4)));
typedef float  floatx4 __attribute__((ext_vector_type(4)));

// log2(e)/sqrt(32): folded into q so softmax runs in exp2 domain
#define QSCALE 0.25506601622184f

// ---------------- K1: fused preact + QKV GEMM, 64x64 tiles ------------------------
// A-tile is built from x (silu on the fly); B-tile from fp32 w_qkv (cvt on the fly).
// Q -> qs[bh][n][d]; K,V -> fragment-major kf/vf (verified R5 layouts).
__launch_bounds__(256)
__global__ void k_qkv(const float* __restrict__ x, const float* __restrict__ wqkv,
                      const float* __restrict__ pab, const float* __restrict__ pqb,
                      const float* __restrict__ bqkv,
                      const float* __restrict__ peqh, const float* __restrict__ peqw,
                      const float* __restrict__ pekh, const float* __restrict__ pekw,
                      const float* __restrict__ mm, const float* __restrict__ mb,
                      __bf16* __restrict__ qs, __bf16* __restrict__ kf, __bf16* __restrict__ vf) {
    __shared__ __bf16 smem[4][64 * 40];  // [a0 a1 b0 b1]; ct (64*72) aliases smem[0..1]
    __bf16* ct = &smem[0][0];
    const int nt = blockIdx.x, ot = blockIdx.y, b = blockIdx.z;   // grid (64, 12, 2)
    const int tid = threadIdx.x;
    const int wave = tid >> 6, lane = tid & 63, ln = lane & 15, quad = lane >> 4;
    const int wm = (wave & 1) * 32, wn = (wave >> 1) * 32;
    floatx4 acc[2][2];
#pragma unroll
    for (int i = 0; i < 2; i++)
#pragma unroll
        for (int j = 0; j < 2; j++) acc[i][j] = 0.f;
    // A staging: cl = c-lane (32), ng = n-group of 8
    const int cl = tid & 31, ng = tid >> 5;
    // B staging: r0 = o-row, c0 = c-chunk
    const int r0 = tid >> 2, c0 = (tid & 3) * 8;
    const float* xsrc = x + (size_t)b * NC * NN + nt * 64 + ng * 8;
    const float* wsrc = wqkv + (size_t)(ot * 64 + r0) * NC + c0;
    float pav = pab[cl], qbv = pqb[cl];
    float4 xa0 = *(const float4*)(xsrc + (size_t)cl * NN);
    float4 xa1 = *(const float4*)(xsrc + (size_t)cl * NN + 4);
    float4 wa0 = *(const float4*)(wsrc);
    float4 wa1 = *(const float4*)(wsrc + 4);
    for (int ko = 0; ko < 8; ko++) {
        int bo = ko & 1;
        // commit A with silu + pre_qkv_bias
        {
            float xs[8] = {xa0.x, xa0.y, xa0.z, xa0.w, xa1.x, xa1.y, xa1.z, xa1.w};
#pragma unroll
            for (int e = 0; e < 8; e++) {
                float s = xs[e] + pav;
                float rr = s / (1.f + __expf(-s)) + qbv;
                smem[bo][(ng * 8 + e) * 40 + cl] = (__bf16)rr;
            }
        }
        // commit B with fp32->bf16 cvt
        {
            bf16x8 wb;
            wb[0] = (__bf16)wa0.x; wb[1] = (__bf16)wa0.y; wb[2] = (__bf16)wa0.z; wb[3] = (__bf16)wa0.w;
            wb[4] = (__bf16)wa1.x; wb[5] = (__bf16)wa1.y; wb[6] = (__bf16)wa1.z; wb[7] = (__bf16)wa1.w;
            *(bf16x8*)(&smem[2 + bo][r0 * 40 + c0]) = wb;
        }
        __syncthreads();
        if (ko < 7) {
            int kc = (ko + 1) * 32;
            pav = pab[kc + cl];
            qbv = pqb[kc + cl];
            xa0 = *(const float4*)(xsrc + (size_t)(kc + cl) * NN);
            xa1 = *(const float4*)(xsrc + (size_t)(kc + cl) * NN + 4);
            wa0 = *(const float4*)(wsrc + kc);
            wa1 = *(const float4*)(wsrc + kc + 4);
        }
        bf16x8 af[2], bfr[2];
#pragma unroll
        for (int ii = 0; ii < 2; ii++) af[ii]  = *(const bf16x8*)(&smem[bo][(wm + ii * 16 + ln) * 40 + quad * 8]);
#pragma unroll
        for (int jj = 0; jj < 2; jj++) bfr[jj] = *(const bf16x8*)(&smem[2 + bo][(wn + jj * 16 + ln) * 40 + quad * 8]);
#pragma unroll
        for (int ii = 0; ii < 2; ii++)
#pragma unroll
            for (int jj = 0; jj < 2; jj++)
                acc[ii][jj] = __builtin_amdgcn_mfma_f32_16x16x32_bf16(af[ii], bfr[jj], acc[ii][jj], 0, 0, 0);
    }
    __syncthreads();   // frag reads done before ct alias written
    if (ot < 8) {
        // Q/K: ct[n_l][o_l]
#pragma unroll
        for (int ii = 0; ii < 2; ii++)
#pragma unroll
            for (int jj = 0; jj < 2; jj++) {
                int o_l = wn + jj * 16 + ln;
                int o_g = ot * 64 + o_l;
                float bq = bqkv[o_g];
#pragma unroll
                for (int r = 0; r < 4; r++) {
                    int n_l = wm + ii * 16 + quad * 4 + r;
                    float val = acc[ii][jj][r] + bq;
                    if (ot < 4) {          // Q: PE + FiLM + softmax scale
                        val += peqh[o_g * 64 + nt] + peqw[o_g * 64 + n_l];
                        val = val * mm[b * NF + o_g] + mb[b * NF + o_g];
                        val *= QSCALE;
                    } else {               // K: PE
                        int c = o_g - 256;
                        val += pekh[c * 64 + nt] + pekw[c * 64 + n_l];
                    }
                    ct[n_l * 72 + o_l] = (__bf16)val;
                }
            }
        __syncthreads();
#pragma unroll
        for (int q = 0; q < 2; q++) {
            int id = tid + q * 256;        // 512 chunks
            int n_l = id >> 3, oc = (id & 7) * 8;
            bf16x8 v = *(const bf16x8*)(ct + n_l * 72 + oc);
            int n_g = nt * 64 + n_l;
            int o_g = ot * 64 + oc;
            if (ot < 4) {
                int h = o_g >> 5, d = o_g & 31;
                *(bf16x8*)(qs + (((size_t)b * NH + h) * NN + n_g) * HSZ + d) = v;
            } else {
                int c = o_g - 256, h = c >> 5, d0 = c & 31;
                size_t blk = ((size_t)(b * NH + h) * 256 + (n_g >> 4)) * 512;
                *(bf16x8*)(kf + blk + (d0 >> 3) * 128 + (n_g & 15) * 8) = v;
            }
        }
    } else {
        // V: ct[o_l][n_l] -> vf fragment-major
#pragma unroll
        for (int ii = 0; ii < 2; ii++)
#pragma unroll
            for (int jj = 0; jj < 2; jj++) {
                int o_l = wn + jj * 16 + ln;
                float bq = bqkv[ot * 64 + o_l];
#pragma unroll
                for (int r = 0; r < 4; r++) {
                    int n_l = wm + ii * 16 + quad * 4 + r;
                    ct[o_l * 72 + n_l] = (__bf16)(acc[ii][jj][r] + bq);
                }
            }
        __syncthreads();
#pragma unroll
        for (int q = 0; q < 4; q++) {
            int id = tid + q * 256;        // 1024 slots of 4 elems
            int o_l = id >> 4, ng4 = (id & 15) * 4;
            bf16x4 v = *(const bf16x4*)(ct + o_l * 72 + ng4);
            int c = (ot - 8) * 64 + o_l, h = c >> 5, d = c & 31;
            int dj = d >> 4, lnv = d & 15;
            int m_g = nt * 64 + ng4;
            size_t blk = ((size_t)(b * NH + h) * 256 + (m_g >> 4)) * 512;
            *(bf16x4*)(vf + blk + (((m_g >> 2) & 3) * 16 + lnv) * 8 + dj * 4) = v;
        }
    }
}

// ---------------- K2: flash attention, split-K x2, 64-q blocks, 16KB LDS ----------
// 2048 blocks = 8/CU -> full theoretical occupancy. 64-key dbuf tiles.
__launch_bounds__(256, 8)
__global__ void k_attn(const __bf16* __restrict__ qs, const __bf16* __restrict__ kf,
                       const __bf16* __restrict__ vf,
                       __bf16* __restrict__ po, float* __restrict__ pl) {
    __shared__ __bf16 sbuf[2 * 4096];     // per buf: [K 2048 | V 2048]
    int bi = blockIdx.x;                  // 2048 blocks
    int xcd = bi & 7, r = bi >> 3;
    int bh = xcd * 2 + (r & 1);           // XCD owns 2 (b,h) pairs -> K/V in its L2
    int r2 = r >> 1;                      // 0..127
    int qt = r2 & 63, half = r2 >> 6;
    int tid = threadIdx.x, wave = tid >> 6, lane = tid & 63, ln = lane & 15, quad = lane >> 4;
    int n0 = qt * 64 + wave * 16;
    const __bf16* qbase = qs + (size_t)bh * NN * HSZ;
    const __bf16* kfb = kf + ((size_t)bh * 256 + half * 128) * 512;
    const __bf16* vfb = vf + ((size_t)bh * 256 + half * 128) * 512;
    bf16x8 qa = *(const bf16x8*)(qbase + (size_t)(n0 + ln) * HSZ + quad * 8);
    floatx4 o[2], o2;
    o[0] = 0.f; o[1] = 0.f; o2 = 0.f;
    floatx4 zf = 0.f;
    s16x4 ones;
    ones[0] = (short)0x3F80; ones[1] = (short)0x3F80;
    ones[2] = (short)0x3F80; ones[3] = (short)0x3F80;   // bf16 1.0
    const int toff = tid * 8;             // 0..2047
    const int lo = lane * 8;
    bf16x8 kr = *(const bf16x8*)(kfb + toff);
    bf16x8 vr = *(const bf16x8*)(vfb + toff);
    for (int mt = 0; mt < 32; mt++) {
        int bo = (mt & 1) << 12;
        *(bf16x8*)(sbuf + bo + toff) = kr;
        *(bf16x8*)(sbuf + bo + 2048 + toff) = vr;
        __syncthreads();                  // single barrier per tile
        if (mt < 31) {
            kr = *(const bf16x8*)(kfb + (mt + 1) * 2048 + toff);
            vr = *(const bf16x8*)(vfb + (mt + 1) * 2048 + toff);
        }
        const __bf16* kl = sbuf + bo;
        const __bf16* vl = sbuf + bo + 2048;
#pragma unroll
        for (int j = 0; j < 4; j++) {
            bf16x8 kfr = *(const bf16x8*)(kl + j * 512 + lo);
            bf16x8 vfr = *(const bf16x8*)(vl + j * 512 + lo);
            s16x4 vb0, vb1;
            __builtin_memcpy(&vb0, &vfr, 8);
            __builtin_memcpy(&vb1, (const char*)&vfr + 8, 8);
            floatx4 s = __builtin_amdgcn_mfma_f32_16x16x32_bf16(kfr, qa, zf, 0, 0, 0);
            bf16x4 p;
#pragma unroll
            for (int rr = 0; rr < 4; rr++)
                p[rr] = (__bf16)__builtin_amdgcn_exp2f(s[rr]);
            s16x4 pa;
            __builtin_memcpy(&pa, &p, 8);
            o[0] = __builtin_amdgcn_mfma_f32_16x16x16bf16_1k(pa, vb0, o[0], 0, 0, 0);
            o[1] = __builtin_amdgcn_mfma_f32_16x16x16bf16_1k(pa, vb1, o[1], 0, 0, 0);
            o2   = __builtin_amdgcn_mfma_f32_16x16x16bf16_1k(pa, ones, o2, 0, 0, 0);
        }
    }
    // o2[rr] = row-sum l for n = n0 + quad*4 + rr (all 16 lanes of quad agree)
    size_t plbase = (size_t)(half * 16 + bh) * NN;
    if (ln == 0)
#pragma unroll
        for (int rr = 0; rr < 4; rr++)
            pl[plbase + n0 + quad * 4 + rr] = o2[rr];
    // po via LDS: ct = buf0 region (last tile mt=31 computed from buf1 -> disjoint)
    __bf16* ct = sbuf;                    // 64*32 = 2048 elems
#pragma unroll
    for (int dj = 0; dj < 2; dj++)
#pragma unroll
        for (int rr = 0; rr < 4; rr++)
            ct[(wave * 16 + quad * 4 + rr) * 32 + dj * 16 + ln] = (__bf16)o[dj][rr];
    __syncthreads();
    size_t pobase = ((size_t)(half * 16 + bh) * NN + (size_t)qt * 64) * HSZ;
    {
        int n_l = tid >> 2, dc = (tid & 3) * 8;
        *(bf16x8*)(po + pobase + n_l * HSZ + dc) = *(const bf16x8*)(ct + n_l * 32 + dc);
    }
}

// ---------------- K3: combine partials + proj GEMM out[o,n] + residual (64x64) ----
__launch_bounds__(256)
__global__ void k_proj(const __bf16* __restrict__ po, const float* __restrict__ pl,
                       const float* __restrict__ wproj, const float* __restrict__ ppb,
                       const float* __restrict__ x, const float* __restrict__ idsc,
                       float* __restrict__ out) {
    __shared__ __bf16 at[64 * 264];    // w_proj tile [64 o][256 f]
    __shared__ __bf16 bt[2][64 * 40];  // combined attn tile [64 n][32 f]
    __shared__ float linv[8 * 64];
    __shared__ float ppbs[256];
    int nt = blockIdx.x, ot = blockIdx.y, b = blockIdx.z;   // grid (64, 4, 2)
    int tid = threadIdx.x, wave = tid >> 6, lane = tid & 63, ln = lane & 15, quad = lane >> 4;
    int wo = (wave & 1) * 32, wn = (wave >> 1) * 32;
#pragma unroll
    for (int q = 0; q < 8; q++) {
        int id = tid + q * 256;
        int row = id >> 5, fc = (id & 31) * 8;
        float4 w0 = *(const float4*)(wproj + (size_t)(ot * 64 + row) * NF + fc);
        float4 w1 = *(const float4*)(wproj + (size_t)(ot * 64 + row) * NF + fc + 4);
        bf16x8 wb;
        wb[0] = (__bf16)w0.x; wb[1] = (__bf16)w0.y; wb[2] = (__bf16)w0.z; wb[3] = (__bf16)w0.w;
        wb[4] = (__bf16)w1.x; wb[5] = (__bf16)w1.y; wb[6] = (__bf16)w1.z; wb[7] = (__bf16)w1.w;
        *(bf16x8*)(at + row * 264 + fc) = wb;
    }
#pragma unroll
    for (int q = 0; q < 2; q++) {
        int id = tid + q * 256;           // 512 = 8h x 64n
        int h = id >> 6, n_l = id & 63;
        size_t base = (size_t)(b * NH + h) * NN + nt * 64 + n_l;
        linv[id] = 1.f / (pl[base] + pl[base + (size_t)16 * NN]);
    }
    ppbs[tid] = ppb[tid];
    __syncthreads();
    floatx4 acc[2][2];
#pragma unroll
    for (int i = 0; i < 2; i++)
#pragma unroll
        for (int j = 0; j < 2; j++) acc[i][j] = 0.f;
    const int n_l = tid >> 2, dh8 = (tid & 3) * 8;
    const size_t hstep = (size_t)NN * HSZ;
    const size_t half_off = (size_t)16 * NN * HSZ;
    size_t prow = ((size_t)b * NH * NN + (size_t)nt * 64 + n_l) * HSZ + dh8;
    bf16x8 p0 = *(const bf16x8*)(po + prow);
    bf16x8 p1 = *(const bf16x8*)(po + prow + half_off);
    for (int ko = 0; ko < 8; ko++) {
        int buf = ko & 1;
        float iv = linv[ko * 64 + n_l];
        bf16x8 c;
#pragma unroll
        for (int e = 0; e < 8; e++)
            c[e] = (__bf16)(((float)p0[e] + (float)p1[e]) * iv + ppbs[ko * 32 + dh8 + e]);
        *(bf16x8*)(&bt[buf][n_l * 40 + dh8]) = c;
        __syncthreads();
        if (ko < 7) {
            size_t pr = prow + (size_t)(ko + 1) * hstep;
            p0 = *(const bf16x8*)(po + pr);
            p1 = *(const bf16x8*)(po + pr + half_off);
        }
        bf16x8 af[2], bfr[2];
#pragma unroll
        for (int oi = 0; oi < 2; oi++) af[oi]  = *(const bf16x8*)(at + (wo + oi * 16 + ln) * 264 + ko * 32 + quad * 8);
#pragma unroll
        for (int nj = 0; nj < 2; nj++) bfr[nj] = *(const bf16x8*)(&bt[buf][(wn + nj * 16 + ln) * 40 + quad * 8]);
#pragma unroll
        for (int oi = 0; oi < 2; oi++)
#pragma unroll
            for (int nj = 0; nj < 2; nj++)
                acc[oi][nj] = __builtin_amdgcn_mfma_f32_16x16x32_bf16(af[oi], bfr[nj], acc[oi][nj], 0, 0, 0);
    }
#pragma unroll
    for (int oi = 0; oi < 2; oi++)
#pragma unroll
        for (int nj = 0; nj < 2; nj++)
#pragma unroll
            for (int r = 0; r < 4; r++) {
                int o_g = ot * 64 + wo + oi * 16 + quad * 4 + r;
                int n_g = nt * 64 + wn + nj * 16 + ln;
                size_t idx = ((size_t)b * NF + o_g) * NN + n_g;
                out[idx] = x[idx] * idsc[o_g] + acc[oi][nj][r];
            }
}

// ---------------- launcher ----------------
extern "C" void kernel_launch(void* const* d_in, const int* in_sizes, int n_in,
                              void* d_out, int out_size, void* d_ws, size_t ws_size,
                              hipStream_t stream) {
    (void)in_sizes; (void)n_in; (void)out_size; (void)ws_size;
    const float* x    = (const float*)d_in[0];
    const float* mm   = (const float*)d_in[1];
    const float* mb   = (const float*)d_in[2];
    const float* wqkv = (const float*)d_in[3];
    const float* bqkv = (const float*)d_in[4];
    const float* wproj= (const float*)d_in[5];
    const float* peqh = (const float*)d_in[6];
    const float* peqw = (const float*)d_in[7];
    const float* pekh = (const float*)d_in[8];
    const float* pekw = (const float*)d_in[9];
    const float* pab  = (const float*)d_in[10];
    const float* pqb  = (const float*)d_in[11];
    const float* ppb  = (const float*)d_in[12];
    const float* idsc = (const float*)d_in[13];
    float* out = (float*)d_out;

    __bf16* ws = (__bf16*)d_ws;
    const size_t SEG = 2097152;            // elements per big buffer
    __bf16* qs   = ws;
    __bf16* kf   = ws + SEG;
    __bf16* vf   = ws + SEG * 2;
    __bf16* po   = ws + SEG * 3;           // 2 halves x 16bh x 4096 x 32 = 4M elems
    float*  pl   = (float*)(ws + SEG * 5); // 131072 floats

    hipLaunchKernelGGL(k_qkv,  dim3(64, 12, 2), dim3(256), 0, stream,
                       x, wqkv, pab, pqb, bqkv, peqh, peqw, pekh, pekw, mm, mb, qs, kf, vf);
    hipLaunchKernelGGL(k_attn, dim3(2048), dim3(256), 0, stream, qs, kf, vf, po, pl);
    hipLaunchKernelGGL(k_proj, dim3(64, 4, 2), dim3(256), 0, stream,
                       po, pl, wproj, ppb, x, idsc, out);
}

// Round 8
// 175.795 us; speedup vs baseline: 1.0114x; 1.0114x over previous
//
#include <hip/hip_runtime.h>
#include <hip/hip_bf16.h>
#include <cstdint>

// Problem constants
#define NB   2
#define NC   256
#define NN   4096   // H*W = 64*64
#define NH   8      // heads
#define HSZ  32     // head size
#define NF   256    // FEAT
#define N3F  768

typedef __bf16 bf16x8 __attribute__((ext_vector_type(8)));
typedef __bf16 bf16x4 __attribute__((ext_vector_type(4)));
typedef short  s16x4  __attribute__((ext_vector_type(4)));
typedef float  floatx4 __attribute__((ext_vector_type(4)));

// log2(e)/sqrt(32): folded into q so softmax runs in exp2 domain
#define QSCALE 0.25506601622184f

// ---------------- K0: prep = preact silu (blocks 0..255) + weight cvt (256..511) --
__global__ void k_prep(const float* __restrict__ x, const float* __restrict__ pab,
                       const float* __restrict__ pqb, __bf16* __restrict__ y,
                       const float* __restrict__ wqkv, const float* __restrict__ wproj,
                       __bf16* __restrict__ wqb, __bf16* __restrict__ wpb) {
    __shared__ __bf16 ct[32 * 264];           // [n][c], stride 264
    int bid = blockIdx.x, tid = threadIdx.x;
    if (bid >= 256) {                         // weight convert: 4 elems/thread
        int id = (bid - 256) * 1024 + tid * 4;
        const float* src = (id < 196608) ? (wqkv + id) : (wproj + (id - 196608));
        __bf16* dst = (id < 196608) ? (wqb + id) : (wpb + (id - 196608));
        float4 v = *(const float4*)src;
        bf16x4 o;
        o[0] = (__bf16)v.x; o[1] = (__bf16)v.y; o[2] = (__bf16)v.z; o[3] = (__bf16)v.w;
        *(bf16x4*)dst = o;
        return;
    }
    int b = bid >> 7, nt = bid & 127;
    int n0 = nt * 32;
    int cbase = tid >> 3, nc = tid & 7;       // n-chunk nc covers 4 n
#pragma unroll
    for (int q = 0; q < 8; q++) {
        int c = cbase + q * 32;
        const float4 xv = *(const float4*)(x + ((size_t)b * NC + c) * NN + n0 + nc * 4);
        float bias = pab[c], qb = pqb[c];
        float vs[4] = {xv.x, xv.y, xv.z, xv.w};
#pragma unroll
        for (int i = 0; i < 4; i++) {
            float s = vs[i] + bias;
            float r = s / (1.f + __expf(-s)) + qb;   // silu + pre_qkv_bias
            ct[(nc * 4 + i) * 264 + c] = (__bf16)r;
        }
    }
    __syncthreads();
#pragma unroll
    for (int q = 0; q < 4; q++) {
        int id = tid + q * 256;               // 1024 chunks
        int n = id >> 5, ck = (id & 31) * 8;
        bf16x8 v = *(const bf16x8*)(ct + n * 264 + ck);
        *(bf16x8*)(y + ((size_t)b * NN + n0 + n) * NC + ck) = v;
    }
}

// ---------------- K1: QKV GEMM, 64x64 tiles (R5-proven) ---------------------------
// kf: per (bh, mt=m/16): 512-elem block; lane l elem (l*8+e) = K[m0 + (l&15)][ (l>>4)*8 + e ]
// vf: per (bh, mt):      512-elem block; elem (l*8 + dj*4 + e) = V[m0 + (l>>4)*4 + e][ dj*16 + (l&15) ]
__launch_bounds__(256)
__global__ void k_qkv(const __bf16* __restrict__ y, const __bf16* __restrict__ wb,
                      const float* __restrict__ bqkv,
                      const float* __restrict__ peqh, const float* __restrict__ peqw,
                      const float* __restrict__ pekh, const float* __restrict__ pekw,
                      const float* __restrict__ mm, const float* __restrict__ mb,
                      __bf16* __restrict__ qs, __bf16* __restrict__ kf, __bf16* __restrict__ vf) {
    __shared__ __bf16 smem[4][64 * 40];  // [a0 a1 b0 b1]; ct (64*72) aliases smem[0..1]
    __bf16* ct = &smem[0][0];
    const int nt = blockIdx.x, ot = blockIdx.y, b = blockIdx.z;   // grid (64, 12, 2)
    const int tid = threadIdx.x;
    const int wave = tid >> 6, lane = tid & 63, ln = lane & 15, quad = lane >> 4;
    const int wm = (wave & 1) * 32, wn = (wave >> 1) * 32;
    floatx4 acc[2][2];
#pragma unroll
    for (int i = 0; i < 2; i++)
#pragma unroll
        for (int j = 0; j < 2; j++) acc[i][j] = 0.f;
    const __bf16* ysrc = y + ((size_t)b * NN + nt * 64) * NC;
    const __bf16* wsrc = wb + (size_t)ot * 64 * NC;
    const int r0 = tid >> 2, c0 = (tid & 3) * 8;
    bf16x8 ya = *(const bf16x8*)(ysrc + (size_t)r0 * NC + c0);
    bf16x8 wa = *(const bf16x8*)(wsrc + (size_t)r0 * NC + c0);
    for (int ko = 0; ko < 8; ko++) {
        int bo = ko & 1;
        *(bf16x8*)(&smem[bo][r0 * 40 + c0]) = ya;
        *(bf16x8*)(&smem[2 + bo][r0 * 40 + c0]) = wa;
        __syncthreads();
        if (ko < 7) {
            int kc = (ko + 1) * 32;
            ya = *(const bf16x8*)(ysrc + (size_t)r0 * NC + kc + c0);
            wa = *(const bf16x8*)(wsrc + (size_t)r0 * NC + kc + c0);
        }
        bf16x8 af[2], bfr[2];
#pragma unroll
        for (int ii = 0; ii < 2; ii++) af[ii]  = *(const bf16x8*)(&smem[bo][(wm + ii * 16 + ln) * 40 + quad * 8]);
#pragma unroll
        for (int jj = 0; jj < 2; jj++) bfr[jj] = *(const bf16x8*)(&smem[2 + bo][(wn + jj * 16 + ln) * 40 + quad * 8]);
#pragma unroll
        for (int ii = 0; ii < 2; ii++)
#pragma unroll
            for (int jj = 0; jj < 2; jj++)
                acc[ii][jj] = __builtin_amdgcn_mfma_f32_16x16x32_bf16(af[ii], bfr[jj], acc[ii][jj], 0, 0, 0);
    }
    __syncthreads();   // frag reads done before ct alias written
    if (ot < 8) {
        // Q/K: ct[n_l][o_l]
#pragma unroll
        for (int ii = 0; ii < 2; ii++)
#pragma unroll
            for (int jj = 0; jj < 2; jj++) {
                int o_l = wn + jj * 16 + ln;
                int o_g = ot * 64 + o_l;
                float bq = bqkv[o_g];
#pragma unroll
                for (int r = 0; r < 4; r++) {
                    int n_l = wm + ii * 16 + quad * 4 + r;
                    float val = acc[ii][jj][r] + bq;
                    if (ot < 4) {          // Q: PE + FiLM + softmax scale
                        val += peqh[o_g * 64 + nt] + peqw[o_g * 64 + n_l];
                        val = val * mm[b * NF + o_g] + mb[b * NF + o_g];
                        val *= QSCALE;
                    } else {               // K: PE
                        int c = o_g - 256;
                        val += pekh[c * 64 + nt] + pekw[c * 64 + n_l];
                    }
                    ct[n_l * 72 + o_l] = (__bf16)val;
                }
            }
        __syncthreads();
#pragma unroll
        for (int q = 0; q < 2; q++) {
            int id = tid + q * 256;        // 512 chunks
            int n_l = id >> 3, oc = (id & 7) * 8;
            bf16x8 v = *(const bf16x8*)(ct + n_l * 72 + oc);
            int n_g = nt * 64 + n_l;
            int o_g = ot * 64 + oc;
            if (ot < 4) {
                int h = o_g >> 5, d = o_g & 31;
                *(bf16x8*)(qs + (((size_t)b * NH + h) * NN + n_g) * HSZ + d) = v;
            } else {
                int c = o_g - 256, h = c >> 5, d0 = c & 31;
                size_t blk = ((size_t)(b * NH + h) * 256 + (n_g >> 4)) * 512;
                *(bf16x8*)(kf + blk + (d0 >> 3) * 128 + (n_g & 15) * 8) = v;
            }
        }
    } else {
        // V: ct[o_l][n_l] -> vf fragment-major
#pragma unroll
        for (int ii = 0; ii < 2; ii++)
#pragma unroll
            for (int jj = 0; jj < 2; jj++) {
                int o_l = wn + jj * 16 + ln;
                float bq = bqkv[ot * 64 + o_l];
#pragma unroll
                for (int r = 0; r < 4; r++) {
                    int n_l = wm + ii * 16 + quad * 4 + r;
                    ct[o_l * 72 + n_l] = (__bf16)(acc[ii][jj][r] + bq);
                }
            }
        __syncthreads();
#pragma unroll
        for (int q = 0; q < 4; q++) {
            int id = tid + q * 256;        // 1024 slots of 4 elems
            int o_l = id >> 4, ng4 = (id & 15) * 4;
            bf16x4 v = *(const bf16x4*)(ct + o_l * 72 + ng4);
            int c = (ot - 8) * 64 + o_l, h = c >> 5, d = c & 31;
            int dj = d >> 4, lnv = d & 15;
            int m_g = nt * 64 + ng4;
            size_t blk = ((size_t)(b * NH + h) * 256 + (m_g >> 4)) * 512;
            *(bf16x4*)(vf + blk + (((m_g >> 2) & 3) * 16 + lnv) * 8 + dj * 4) = v;
        }
    }
}

// ---------------- K2: flash attention, split-K x2, 2 Q-frags, 64-key tiles --------
// 1024 blocks = 4/CU; 16 KB LDS; VALU lsum (PV pipe freed from ones-MFMA).
__launch_bounds__(256, 6)
__global__ void k_attn(const __bf16* __restrict__ qs, const __bf16* __restrict__ kf,
                       const __bf16* __restrict__ vf,
                       __bf16* __restrict__ po, float* __restrict__ pl) {
    __shared__ __bf16 sbuf[2 * 4096];     // per buf: [K 2048 | V 2048] elems
    int bi = blockIdx.x;                  // 1024 blocks
    int xcd = bi & 7, r = bi >> 3;
    int bh = xcd * 2 + (r & 1);           // XCD owns 2 (b,h) pairs -> K/V in its L2
    int r2 = r >> 1;                      // 0..63
    int qt = r2 & 31, half = r2 >> 5;
    int tid = threadIdx.x, wave = tid >> 6, lane = tid & 63, ln = lane & 15, quad = lane >> 4;
    int n0 = qt * 128 + wave * 32;
    const __bf16* qbase = qs + (size_t)bh * NN * HSZ;
    const __bf16* kfb = kf + ((size_t)bh * 256 + half * 128) * 512;
    const __bf16* vfb = vf + ((size_t)bh * 256 + half * 128) * 512;
    bf16x8 qa[2];
    qa[0] = *(const bf16x8*)(qbase + (size_t)(n0 + ln) * HSZ + quad * 8);
    qa[1] = *(const bf16x8*)(qbase + (size_t)(n0 + 16 + ln) * HSZ + quad * 8);
    floatx4 o[2][2];
    o[0][0] = 0.f; o[0][1] = 0.f; o[1][0] = 0.f; o[1][1] = 0.f;
    floatx4 lsum4[2];
    lsum4[0] = 0.f; lsum4[1] = 0.f;
    floatx4 zf = 0.f;
    const int toff = tid * 8;             // 0..2047
    const int lo = lane * 8;
    bf16x8 kr = *(const bf16x8*)(kfb + toff);
    bf16x8 vr = *(const bf16x8*)(vfb + toff);
    for (int mt = 0; mt < 32; mt++) {
        int bo = (mt & 1) << 12;
        *(bf16x8*)(sbuf + bo + toff) = kr;
        *(bf16x8*)(sbuf + bo + 2048 + toff) = vr;
        __syncthreads();                  // single barrier per tile
        if (mt < 31) {
            kr = *(const bf16x8*)(kfb + (mt + 1) * 2048 + toff);
            vr = *(const bf16x8*)(vfb + (mt + 1) * 2048 + toff);
        }
        const __bf16* kl = sbuf + bo;
        const __bf16* vl = sbuf + bo + 2048;
#pragma unroll
        for (int j = 0; j < 4; j++) {
            bf16x8 kfr = *(const bf16x8*)(kl + j * 512 + lo);
            bf16x8 vfr = *(const bf16x8*)(vl + j * 512 + lo);
            s16x4 vb0, vb1;
            __builtin_memcpy(&vb0, &vfr, 8);
            __builtin_memcpy(&vb1, (const char*)&vfr + 8, 8);
#pragma unroll
            for (int i = 0; i < 2; i++) {
                floatx4 s = __builtin_amdgcn_mfma_f32_16x16x32_bf16(kfr, qa[i], zf, 0, 0, 0);
                bf16x4 p;
#pragma unroll
                for (int rr = 0; rr < 4; rr++) {
                    float e = __builtin_amdgcn_exp2f(s[rr]);
                    lsum4[i][rr] += e;
                    p[rr] = (__bf16)e;
                }
                s16x4 pa;
                __builtin_memcpy(&pa, &p, 8);
                o[i][0] = __builtin_amdgcn_mfma_f32_16x16x16bf16_1k(pa, vb0, o[i][0], 0, 0, 0);
                o[i][1] = __builtin_amdgcn_mfma_f32_16x16x16bf16_1k(pa, vb1, o[i][1], 0, 0, 0);
            }
        }
    }
    // row-sums: per lane partial for n = ln (its quad's m-sets); reduce across quads
    size_t plbase = (size_t)(half * 16 + bh) * NN;
#pragma unroll
    for (int i = 0; i < 2; i++) {
        float ls = lsum4[i][0] + lsum4[i][1] + lsum4[i][2] + lsum4[i][3];
        ls += __shfl_xor(ls, 16, 64);
        ls += __shfl_xor(ls, 32, 64);
        if (quad == 0) pl[plbase + n0 + i * 16 + ln] = ls;
    }
    // po via LDS: ct = buf0 region (last tile mt=31 computed from buf1 -> disjoint)
    __bf16* ct = sbuf;                    // 128*32 = 4096 elems
#pragma unroll
    for (int i = 0; i < 2; i++)
#pragma unroll
        for (int dj = 0; dj < 2; dj++)
#pragma unroll
            for (int rr = 0; rr < 4; rr++)
                ct[(wave * 32 + i * 16 + quad * 4 + rr) * 32 + dj * 16 + ln] = (__bf16)o[i][dj][rr];
    __syncthreads();
    size_t pobase = ((size_t)(half * 16 + bh) * NN + (size_t)qt * 128) * HSZ;
#pragma unroll
    for (int q = 0; q < 2; q++) {
        int id = tid + q * 256;           // 512 chunks
        int n_l = id >> 2, dc = (id & 3) * 8;
        *(bf16x8*)(po + pobase + n_l * HSZ + dc) = *(const bf16x8*)(ct + n_l * 32 + dc);
    }
}

// ---------------- K3: combine + proj GEMM + residual; 512 threads, 64x64 tile -----
__launch_bounds__(512)
__global__ void k_proj(const __bf16* __restrict__ po, const float* __restrict__ pl,
                       const __bf16* __restrict__ wpb, const float* __restrict__ ppb,
                       const float* __restrict__ x, const float* __restrict__ idsc,
                       float* __restrict__ out) {
    __shared__ __bf16 at[64 * 264];    // w_proj tile [64 o][256 f]
    __shared__ __bf16 bt[2][64 * 40];  // combined attn tile [64 n][32 f]
    __shared__ float linv[8 * 64];
    __shared__ float ppbs[256];
    int nt = blockIdx.x, ot = blockIdx.y, b = blockIdx.z;   // grid (64, 4, 2)
    int tid = threadIdx.x, wave = tid >> 6, lane = tid & 63, ln = lane & 15, quad = lane >> 4;
    int wo = (wave & 1) * 32, wn = (wave >> 1) * 16;        // 2x4 wave grid over 64o x 64n
#pragma unroll
    for (int q = 0; q < 4; q++) {
        int id = tid + q * 512;           // 2048 chunks
        int row = id >> 5, fc = (id & 31) * 8;
        *(bf16x8*)(at + row * 264 + fc) = *(const bf16x8*)(wpb + (size_t)(ot * 64 + row) * NF + fc);
    }
    {
        int h = tid >> 6, n_l = tid & 63; // 512 = 8h x 64n
        size_t base = (size_t)(b * NH + h) * NN + nt * 64 + n_l;
        linv[tid] = 1.f / (pl[base] + pl[base + (size_t)16 * NN]);
        if (tid < 256) ppbs[tid] = ppb[tid];
    }
    __syncthreads();
    floatx4 acc[2];
    acc[0] = 0.f; acc[1] = 0.f;
    // combine staging: thread -> n_l = tid>>3, 4-elem d-chunk
    const int n_l = tid >> 3, dh4 = (tid & 7) * 4;
    const size_t hstep = (size_t)NN * HSZ;
    const size_t half_off = (size_t)16 * NN * HSZ;
    size_t prow = ((size_t)b * NH * NN + (size_t)nt * 64 + n_l) * HSZ + dh4;
    bf16x4 p0 = *(const bf16x4*)(po + prow);
    bf16x4 p1 = *(const bf16x4*)(po + prow + half_off);
    for (int ko = 0; ko < 8; ko++) {
        int buf = ko & 1;
        float iv = linv[ko * 64 + n_l];
        bf16x4 c;
#pragma unroll
        for (int e = 0; e < 4; e++)
            c[e] = (__bf16)(((float)p0[e] + (float)p1[e]) * iv + ppbs[ko * 32 + dh4 + e]);
        *(bf16x4*)(&bt[buf][n_l * 40 + dh4]) = c;
        __syncthreads();
        if (ko < 7) {
            size_t pr = prow + (size_t)(ko + 1) * hstep;
            p0 = *(const bf16x4*)(po + pr);
            p1 = *(const bf16x4*)(po + pr + half_off);
        }
        bf16x8 af[2], bfr;
#pragma unroll
        for (int oi = 0; oi < 2; oi++) af[oi] = *(const bf16x8*)(at + (wo + oi * 16 + ln) * 264 + ko * 32 + quad * 8);
        bfr = *(const bf16x8*)(&bt[buf][(wn + ln) * 40 + quad * 8]);
#pragma unroll
        for (int oi = 0; oi < 2; oi++)
            acc[oi] = __builtin_amdgcn_mfma_f32_16x16x32_bf16(af[oi], bfr, acc[oi], 0, 0, 0);
    }
#pragma unroll
    for (int oi = 0; oi < 2; oi++)
#pragma unroll
        for (int r = 0; r < 4; r++) {
            int o_g = ot * 64 + wo + oi * 16 + quad * 4 + r;
            int n_g = nt * 64 + wn + ln;
            size_t idx = ((size_t)b * NF + o_g) * NN + n_g;
            out[idx] = x[idx] * idsc[o_g] + acc[oi][r];
        }
}

// ---------------- launcher ----------------
extern "C" void kernel_launch(void* const* d_in, const int* in_sizes, int n_in,
                              void* d_out, int out_size, void* d_ws, size_t ws_size,
                              hipStream_t stream) {
    (void)in_sizes; (void)n_in; (void)out_size; (void)ws_size;
    const float* x    = (const float*)d_in[0];
    const float* mm   = (const float*)d_in[1];
    const float* mb   = (const float*)d_in[2];
    const float* wqkv = (const float*)d_in[3];
    const float* bqkv = (const float*)d_in[4];
    const float* wproj= (const float*)d_in[5];
    const float* peqh = (const float*)d_in[6];
    const float* peqw = (const float*)d_in[7];
    const float* pekh = (const float*)d_in[8];
    const float* pekw = (const float*)d_in[9];
    const float* pab  = (const float*)d_in[10];
    const float* pqb  = (const float*)d_in[11];
    const float* ppb  = (const float*)d_in[12];
    const float* idsc = (const float*)d_in[13];
    float* out = (float*)d_out;

    __bf16* ws = (__bf16*)d_ws;
    const size_t SEG = 2097152;            // elements per big buffer
    __bf16* y    = ws;
    __bf16* qs   = ws + SEG;
    __bf16* kf   = ws + SEG * 2;
    __bf16* vf   = ws + SEG * 3;
    __bf16* po   = ws + SEG * 4;           // 2 halves x 16bh x 4096 x 32 = 4M elems
    float*  pl   = (float*)(ws + SEG * 6); // 131072 floats
    __bf16* wqb  = ws + SEG * 6 + 262144;
    __bf16* wpb  = wqb + 196608;

    hipLaunchKernelGGL(k_prep, dim3(512), dim3(256), 0, stream,
                       x, pab, pqb, y, wqkv, wproj, wqb, wpb);
    hipLaunchKernelGGL(k_qkv,  dim3(64, 12, 2), dim3(256), 0, stream,
                       y, wqb, bqkv, peqh, peqw, pekh, pekw, mm, mb, qs, kf, vf);
    hipLaunchKernelGGL(k_attn, dim3(1024), dim3(256), 0, stream, qs, kf, vf, po, pl);
    hipLaunchKernelGGL(k_proj, dim3(64, 4, 2), dim3(512), 0, stream,
                       po, pl, wpb, ppb, x, idsc, out);
}